// Round 8
// baseline (197.079 us; speedup 1.0000x reference)
//
#include <hip/hip_runtime.h>

// ---------------------------------------------------------------------------
// MoE "brain" model via MFMA 32x32x16 f16.
// One wave = 2 tiles x 32 samples (N dim). Features ride the M dim.
// Slot-permutation trick: layer outputs (C layout) are relu'd + packed and fed
// directly as the next layer's B operand; a prep kernel pre-permutes weights
// into A-fragments whose K-slot assignment matches the C-register pattern:
//   feat(reg r, half h) = (r&3) + 8*(r>>2) + 4*h   (C/D layout, HW-verified)
// Biases folded into spare K slots (B slot = 1.0) or a bias-MFMA step (b2).
// R8: = R6 (best, 79us dispatch) + Z zero-tuple pinned into AGPRs ("+a").
// R7 evidence: prep kernel launch is FREE (82us bench-dispatch gap is fixed
// harness overhead), in-kernel prep costs +8us, "+v" pins only add copies.
// Theory: MFMA chain-heads with C=Z copy Z into the AGPR dst (16
// v_accvgpr_write x 60 heads/iter). With Z already in AGPRs, D!=C MFMA needs
// no copies -> ~960 VALU inst/iter saved.
// ---------------------------------------------------------------------------

#define B_TOTAL 1048576
#define NFRAG   60
#define FRAG_U4 (NFRAG * 64)   // 3840 x 16B = 61440 B

typedef _Float16 f16x8 __attribute__((ext_vector_type(8)));
typedef __fp16   fp16x2 __attribute__((ext_vector_type(2)));
typedef float    f32x16 __attribute__((ext_vector_type(16)));
typedef unsigned int u32x4v __attribute__((ext_vector_type(4)));

#define MFMA(a, b, c) __builtin_amdgcn_mfma_f32_32x32x16_f16((a), (b), (c), 0, 0, 0)

__device__ __forceinline__ unsigned pkrtz_u(float a, float b) {
    fp16x2 t = __builtin_amdgcn_cvt_pkrtz(a, b);
    return __builtin_bit_cast(unsigned, t);
}
// f32 pair -> f16x2 with relu: 1 v_cvt_pkrtz + 1 v_pk_max_f16
__device__ __forceinline__ unsigned pkru(float a, float b) {
    fp16x2 t = __builtin_amdgcn_cvt_pkrtz(a, b);
    fp16x2 z = {(__fp16)0.f, (__fp16)0.f};
    fp16x2 m = __builtin_elementwise_max(t, z);
    return __builtin_bit_cast(unsigned, m);
}
__device__ __forceinline__ f16x8 mk4(unsigned a, unsigned b, unsigned c, unsigned d) {
    u32x4v t; t.x = a; t.y = b; t.z = c; t.w = d;
    return __builtin_bit_cast(f16x8, t);
}
// relu + pack 16 f32 accum regs -> 8 u32 (f16x2); C reg 2i,2i+1 -> p[i]
__device__ __forceinline__ void packrelu(const f32x16& c, unsigned* p) {
    #pragma unroll
    for (int i = 0; i < 8; ++i)
        p[i] = pkru(c[2 * i], c[2 * i + 1]);
}
__device__ __forceinline__ float tanh_fast(float v) {
    v = fminf(fmaxf(v, -10.f), 10.f);
    float e = __expf(2.f * v);
    return __fdividef(e - 1.f, e + 1.f);
}

// ---------------------------------------------------------------------------
// Prep kernel: build permuted f16 A-fragments in d_ws. (same as R6)
// Frag map:
//   0,1     : gate L1 tiles (G1 + gb1 in phi_x bias slot)
//   2..5    : gate L2 steps 0-3 (G2)
//   6,7     : refine L1 tiles (R1 + rb1 in psi bias slot)
//   8..11   : refine L2 steps 0-3 (R2)
//   12+6e+0 : expert e W1 (phi_x + b1 bias slot)
//   12+6e+1,2: expert e W2 steps 0,1 (phi_h)
//   12+6e+3 : expert e b2 bias frag (slot h=0,j=0)
//   12+6e+4,5: expert e W3 steps 0,1 (phi_h), rows m<2
// ---------------------------------------------------------------------------
__global__ void prep_kernel(const float* __restrict__ W1, const float* __restrict__ b1,
                            const float* __restrict__ W2, const float* __restrict__ b2,
                            const float* __restrict__ W3, const float* __restrict__ b3,
                            const float* __restrict__ G1, const float* __restrict__ gb1,
                            const float* __restrict__ G2, const float* __restrict__ gb2,
                            const float* __restrict__ R1, const float* __restrict__ rb1,
                            const float* __restrict__ R2, const float* __restrict__ rb2,
                            _Float16* __restrict__ ws)
{
    int gid = blockIdx.x * 256 + threadIdx.x;
    if (gid >= NFRAG * 64) return;
    int f = gid >> 6, lane = gid & 63;
    int m = lane & 31, h = lane >> 5;
    float v[8];
    #pragma unroll
    for (int j = 0; j < 8; ++j) v[j] = 0.f;

    if (f < 2) {                       // gate L1, phi_x, tile m-offset f*32
        int mo = f * 32 + m;
        for (int j = 0; j < 8; ++j) {
            if (h == 0)       v[j] = G1[j * 64 + mo];
            else if (j < 2)   v[j] = G1[(8 + j) * 64 + mo];
            else if (j == 2)  v[j] = gb1[mo];
        }
    } else if (f < 6) {                // gate L2 (K=64), step s
        int s = f - 2;
        for (int j = 0; j < 8; ++j) {
            int k = 32 * (s >> 1) + 16 * (s & 1) + (j & 3) + 8 * (j >> 2) + 4 * h;
            v[j] = (m < 8) ? G2[k * 8 + m] : 0.f;
        }
    } else if (f < 8) {                // refine L1, psi, tile m-offset (f-6)*32
        int mo = (f - 6) * 32 + m;
        for (int j = 0; j < 8; ++j) {
            if (h == 0)       v[j] = R1[j * 64 + mo];        // rows 0,1=fused; 2..7=x0..x5
            else if (j < 4)   v[j] = R1[(8 + j) * 64 + mo];  // rows 8..11 = x6..x9
            else if (j == 4)  v[j] = rb1[mo];
        }
    } else if (f < 12) {               // refine L2 (K=64), step s
        int s = f - 8;
        for (int j = 0; j < 8; ++j) {
            int k = 32 * (s >> 1) + 16 * (s & 1) + (j & 3) + 8 * (j >> 2) + 4 * h;
            v[j] = (m < 2) ? R2[k * 2 + m] : 0.f;
        }
    } else {                           // experts
        int e = (f - 12) / 6, t = (f - 12) % 6;
        if (t == 0) {                  // W1 phi_x + b1
            for (int j = 0; j < 8; ++j) {
                if (h == 0)       v[j] = W1[e * 320 + j * 32 + m];
                else if (j < 2)   v[j] = W1[e * 320 + (8 + j) * 32 + m];
                else if (j == 2)  v[j] = b1[e * 32 + m];
            }
        } else if (t == 1 || t == 2) { // W2 step s, phi_h
            int s = t - 1;
            for (int j = 0; j < 8; ++j) {
                int k = 16 * s + (j & 3) + 8 * (j >> 2) + 4 * h;
                v[j] = W2[e * 1024 + k * 32 + m];
            }
        } else if (t == 3) {           // b2 bias frag
            if (h == 0) v[0] = b2[e * 32 + m];
        } else {                       // W3 step s, phi_h
            int s = t - 4;
            for (int j = 0; j < 8; ++j) {
                int k = 16 * s + (j & 3) + 8 * (j >> 2) + 4 * h;
                v[j] = (m < 2) ? W3[e * 64 + k * 2 + m] : 0.f;
            }
        }
    }
    _Float16* dst = ws + (size_t)(f * 64 + lane) * 8;
    #pragma unroll
    for (int j = 0; j < 8; ++j) dst[j] = (_Float16)v[j];
}

// ---------------------------------------------------------------------------
// Main kernel: block = 1024 threads = 16 waves, 64 samples/wave (2 tiles).
// ---------------------------------------------------------------------------
__global__ __launch_bounds__(1024, 2) void brain_mfma(
    const float* __restrict__ x,
    const u32x4v* __restrict__ wsf,
    const float* __restrict__ b3, const float* __restrict__ gb2,
    const float* __restrict__ rb2,
    float* __restrict__ out)
{
    __shared__ u32x4v smem[FRAG_U4];
    const int tid = threadIdx.x;
    for (int i = tid; i < FRAG_U4; i += 1024) smem[i] = wsf[i];
    __syncthreads();

    const int lane = tid & 63;
    const int wv   = tid >> 6;
    const int n    = lane & 31;
    const int h    = lane >> 5;
    const size_t sA = (size_t)blockIdx.x * 1024 + wv * 64 + n;  // tile A
    const size_t sB = sA + 32;                                   // tile B

    const unsigned ONEZERO = 0x00003C00u;  // f16 {1.0, 0.0}

    // ---- per-tile x load + fragment build ----
    const float2* xpA = (const float2*)(x + sA * 10);
    const float2* xpB = (const float2*)(x + sB * 10);
    float2 A0 = xpA[h ? 3 : 0], A1 = xpA[h ? 4 : 1], A2 = xpA[h ? 4 : 2], A3 = xpA[3];
    float2 B0 = xpB[h ? 3 : 0], B1 = xpB[h ? 4 : 1], B2 = xpB[h ? 4 : 2], B3 = xpB[3];

    unsigned pkAa = pkrtz_u(A0.x, A0.y), pkAb = pkrtz_u(A1.x, A1.y);
    unsigned pkAc = pkrtz_u(A2.x, A2.y), pkAd = pkrtz_u(A3.x, A3.y);
    unsigned pkBa = pkrtz_u(B0.x, B0.y), pkBb = pkrtz_u(B1.x, B1.y);
    unsigned pkBc = pkrtz_u(B2.x, B2.y), pkBd = pkrtz_u(B3.x, B3.y);

    // layer-1 x fragment (phi_x): lo {x0..x7}, hi {x8,x9,1,0,...}
    f16x8 xfA = h ? mk4(pkAb, ONEZERO, 0u, 0u) : mk4(pkAa, pkAb, pkAc, pkAd);
    f16x8 xfB = h ? mk4(pkBb, ONEZERO, 0u, 0u) : mk4(pkBa, pkBb, pkBc, pkBd);

    const f16x8 ONES = mk4(0x3C003C00u, 0x3C003C00u, 0x3C003C00u, 0x3C003C00u);
    // Zero C-tuple pinned into AGPRs: MFMA heads read C=Z directly from the
    // AGPR file, so no per-head zero-materialization copies are needed.
    f32x16 Z;
    #pragma unroll
    for (int i = 0; i < 16; ++i) Z[i] = 0.f;
    asm("" : "+a"(Z));

    #define FRAG(F) __builtin_bit_cast(f16x8, smem[(F) * 64 + lane])

    // ---------------- gate (both tiles) ----------------
    float wA[8], wB[8];
    {
        f16x8 g0 = FRAG(0), g1 = FRAG(1);
        f32x16 cg0A = MFMA(g0, xfA, Z), cg1A = MFMA(g1, xfA, Z);
        f32x16 cg0B = MFMA(g0, xfB, Z), cg1B = MFMA(g1, xfB, Z);
        unsigned p0A[8], p1A[8], p0B[8], p1B[8];
        packrelu(cg0A, p0A); packrelu(cg1A, p1A);
        packrelu(cg0B, p0B); packrelu(cg1B, p1B);
        f16x8 l0 = FRAG(2), l1 = FRAG(3), l2 = FRAG(4), l3 = FRAG(5);
        f32x16 clA = MFMA(l0, mk4(p0A[0], p0A[1], p0A[2], p0A[3]), Z);
        clA = MFMA(l1, mk4(p0A[4], p0A[5], p0A[6], p0A[7]), clA);
        clA = MFMA(l2, mk4(p1A[0], p1A[1], p1A[2], p1A[3]), clA);
        clA = MFMA(l3, mk4(p1A[4], p1A[5], p1A[6], p1A[7]), clA);
        f32x16 clB = MFMA(l0, mk4(p0B[0], p0B[1], p0B[2], p0B[3]), Z);
        clB = MFMA(l1, mk4(p0B[4], p0B[5], p0B[6], p0B[7]), clB);
        clB = MFMA(l2, mk4(p1B[0], p1B[1], p1B[2], p1B[3]), clB);
        clB = MFMA(l3, mk4(p1B[4], p1B[5], p1B[6], p1B[7]), clB);

        // logits: low lanes regs0-3 = experts0-3; high lanes = experts4-7
        float lA[8], lB[8];
        #pragma unroll
        for (int j = 0; j < 4; ++j) {
            lA[j]     = clA[j] + gb2[j];
            lA[4 + j] = __shfl_xor(clA[j], 32) + gb2[4 + j];
            lB[j]     = clB[j] + gb2[j];
            lB[4 + j] = __shfl_xor(clB[j], 32) + gb2[4 + j];
        }
        float mxA = lA[0], mxB = lB[0];
        #pragma unroll
        for (int j = 1; j < 8; ++j) { mxA = fmaxf(mxA, lA[j]); mxB = fmaxf(mxB, lB[j]); }
        float sA_ = 0.f, sB_ = 0.f;
        #pragma unroll
        for (int j = 0; j < 8; ++j) {
            wA[j] = __expf(lA[j] - mxA); sA_ += wA[j];
            wB[j] = __expf(lB[j] - mxB); sB_ += wB[j];
        }
        float invA = __fdividef(1.f, sA_), invB = __fdividef(1.f, sB_);
        #pragma unroll
        for (int j = 0; j < 8; ++j) { wA[j] *= invA; wB[j] *= invB; }
    }

    // ---------------- experts (both tiles share frag reads) ----------------
    float fA0 = 0.f, fA1 = 0.f, fB0 = 0.f, fB1 = 0.f;
    #pragma unroll 1
    for (int e = 0; e < 8; ++e) {
        const int fb = 12 + e * 6;
        f16x8 a0 = FRAG(fb);
        f32x16 c1A = MFMA(a0, xfA, Z);
        f32x16 c1B = MFMA(a0, xfB, Z);
        unsigned qA[8], qB[8];
        packrelu(c1A, qA); packrelu(c1B, qB);

        f16x8 a1 = FRAG(fb + 1), a2 = FRAG(fb + 2), a3 = FRAG(fb + 3);
        f32x16 c2A = MFMA(a1, mk4(qA[0], qA[1], qA[2], qA[3]), Z);
        c2A = MFMA(a2, mk4(qA[4], qA[5], qA[6], qA[7]), c2A);
        c2A = MFMA(a3, ONES, c2A);                              // + b2
        f32x16 c2B = MFMA(a1, mk4(qB[0], qB[1], qB[2], qB[3]), Z);
        c2B = MFMA(a2, mk4(qB[4], qB[5], qB[6], qB[7]), c2B);
        c2B = MFMA(a3, ONES, c2B);
        packrelu(c2A, qA); packrelu(c2B, qB);

        f16x8 a4 = FRAG(fb + 4), a5 = FRAG(fb + 5);
        f32x16 c3A = MFMA(a4, mk4(qA[0], qA[1], qA[2], qA[3]), Z);
        c3A = MFMA(a5, mk4(qA[4], qA[5], qA[6], qA[7]), c3A);
        f32x16 c3B = MFMA(a4, mk4(qB[0], qB[1], qB[2], qB[3]), Z);
        c3B = MFMA(a5, mk4(qB[4], qB[5], qB[6], qB[7]), c3B);

        float b30 = b3[2 * e], b31 = b3[2 * e + 1];
        fA0 = fmaf(wA[e], tanh_fast(c3A[0] + b30), fA0);
        fA1 = fmaf(wA[e], tanh_fast(c3A[1] + b31), fA1);
        fB0 = fmaf(wB[e], tanh_fast(c3B[0] + b30), fB0);
        fB1 = fmaf(wB[e], tanh_fast(c3B[1] + b31), fB1);
    }

    // ---------------- refine (both tiles) ----------------
    // psi layout: lo {FUSED, x0x1, x2x3, x4x5}, hi {x6x7, x8x9, {1,0}, 0}
    unsigned rxA0 = h ? pkAa : pkrtz_u(fA0, fA1);
    unsigned rxB0 = h ? pkBa : pkrtz_u(fB0, fB1);
    unsigned rxA1 = h ? pkAb : pkAa, rxA2 = h ? ONEZERO : pkAb, rxA3 = h ? 0u : pkAc;
    unsigned rxB1 = h ? pkBb : pkBa, rxB2 = h ? ONEZERO : pkBb, rxB3 = h ? 0u : pkBc;
    f16x8 rfA = mk4(rxA0, rxA1, rxA2, rxA3);
    f16x8 rfB = mk4(rxB0, rxB1, rxB2, rxB3);

    f16x8 r0 = FRAG(6), r1 = FRAG(7);
    f32x16 cr0A = MFMA(r0, rfA, Z), cr1A = MFMA(r1, rfA, Z);
    f32x16 cr0B = MFMA(r0, rfB, Z), cr1B = MFMA(r1, rfB, Z);
    unsigned p0A[8], p1A[8], p0B[8], p1B[8];
    packrelu(cr0A, p0A); packrelu(cr1A, p1A);
    packrelu(cr0B, p0B); packrelu(cr1B, p1B);

    f16x8 d0 = FRAG(8), d1 = FRAG(9), d2 = FRAG(10), d3 = FRAG(11);
    f32x16 cdA = MFMA(d0, mk4(p0A[0], p0A[1], p0A[2], p0A[3]), Z);
    cdA = MFMA(d1, mk4(p0A[4], p0A[5], p0A[6], p0A[7]), cdA);
    cdA = MFMA(d2, mk4(p1A[0], p1A[1], p1A[2], p1A[3]), cdA);
    cdA = MFMA(d3, mk4(p1A[4], p1A[5], p1A[6], p1A[7]), cdA);
    f32x16 cdB = MFMA(d0, mk4(p0B[0], p0B[1], p0B[2], p0B[3]), Z);
    cdB = MFMA(d1, mk4(p0B[4], p0B[5], p0B[6], p0B[7]), cdB);
    cdB = MFMA(d2, mk4(p1B[0], p1B[1], p1B[2], p1B[3]), cdB);
    cdB = MFMA(d3, mk4(p1B[4], p1B[5], p1B[6], p1B[7]), cdB);

    if (h == 0) {
        float2 oA, oB;
        oA.x = tanh_fast(cdA[0] + rb2[0]);
        oA.y = tanh_fast(cdA[1] + rb2[1]);
        oB.x = tanh_fast(cdB[0] + rb2[0]);
        oB.y = tanh_fast(cdB[1] + rb2[1]);
        ((float2*)out)[sA] = oA;
        ((float2*)out)[sB] = oB;
    }
}

extern "C" void kernel_launch(void* const* d_in, const int* in_sizes, int n_in,
                              void* d_out, int out_size, void* d_ws, size_t ws_size,
                              hipStream_t stream) {
    const float* x   = (const float*)d_in[0];
    const float* W1  = (const float*)d_in[1];
    const float* b1  = (const float*)d_in[2];
    const float* W2  = (const float*)d_in[3];
    const float* b2  = (const float*)d_in[4];
    const float* W3  = (const float*)d_in[5];
    const float* b3  = (const float*)d_in[6];
    const float* G1  = (const float*)d_in[7];
    const float* gb1 = (const float*)d_in[8];
    const float* G2  = (const float*)d_in[9];
    const float* gb2 = (const float*)d_in[10];
    const float* R1  = (const float*)d_in[11];
    const float* rb1 = (const float*)d_in[12];
    const float* R2  = (const float*)d_in[13];
    const float* rb2 = (const float*)d_in[14];
    float* out = (float*)d_out;
    _Float16* ws = (_Float16*)d_ws;

    hipLaunchKernelGGL(prep_kernel, dim3(15), dim3(256), 0, stream,
                       W1, b1, W2, b2, W3, b3, G1, gb1, G2, gb2, R1, rb1, R2, rb2, ws);
    hipLaunchKernelGGL(brain_mfma, dim3(B_TOTAL / 1024), dim3(1024), 0, stream,
                       x, (const u32x4v*)ws, b3, gb2, rb2, out);
}

// Round 9
// 159.065 us; speedup vs baseline: 1.2390x; 1.2390x over previous
//
#include <hip/hip_runtime.h>

// ---------------------------------------------------------------------------
// MoE "brain" model via MFMA 32x32x16 f16.
// One wave = 2 tiles x 32 samples (N dim). Features ride the M dim.
// Slot-permutation trick: layer outputs (C layout) are relu'd + packed and fed
// directly as the next layer's B operand; a prep kernel pre-permutes weights
// into A-fragments whose K-slot assignment matches the C-register pattern:
//   feat(reg r, half h) = (r&3) + 8*(r>>2) + 4*h   (C/D layout, HW-verified)
// Biases folded into spare K slots (B slot = 1.0) or a bias-MFMA step (b2).
// R9: = R6 kernel body, but block=512 / __launch_bounds__(512,1).
// Rationale: R6's (1024,2)=256-reg budget makes the RA pre-split
// Arch=64/AGPR=192 -> ~1,800 inst/wave of accvgpr zero-init/read churn AND
// caps occupancy at ~9 waves/CU (reg-bound). A 512-reg budget lets all ~170
// live regs sit in the arch partition (no churn); LDS (60KB) then allows
// 2 blocks/CU = 16 waves/CU. R7/R8 showed asm pins only add copies/spills --
// this changes the budget instead of fighting the allocator.
// ---------------------------------------------------------------------------

#define B_TOTAL 1048576
#define NFRAG   60
#define FRAG_U4 (NFRAG * 64)   // 3840 x 16B = 61440 B

typedef _Float16 f16x8 __attribute__((ext_vector_type(8)));
typedef __fp16   fp16x2 __attribute__((ext_vector_type(2)));
typedef float    f32x16 __attribute__((ext_vector_type(16)));
typedef unsigned int u32x4v __attribute__((ext_vector_type(4)));

#define MFMA(a, b, c) __builtin_amdgcn_mfma_f32_32x32x16_f16((a), (b), (c), 0, 0, 0)

__device__ __forceinline__ unsigned pkrtz_u(float a, float b) {
    fp16x2 t = __builtin_amdgcn_cvt_pkrtz(a, b);
    return __builtin_bit_cast(unsigned, t);
}
// f32 pair -> f16x2 with relu: 1 v_cvt_pkrtz + 1 v_pk_max_f16
__device__ __forceinline__ unsigned pkru(float a, float b) {
    fp16x2 t = __builtin_amdgcn_cvt_pkrtz(a, b);
    fp16x2 z = {(__fp16)0.f, (__fp16)0.f};
    fp16x2 m = __builtin_elementwise_max(t, z);
    return __builtin_bit_cast(unsigned, m);
}
__device__ __forceinline__ f16x8 mk4(unsigned a, unsigned b, unsigned c, unsigned d) {
    u32x4v t; t.x = a; t.y = b; t.z = c; t.w = d;
    return __builtin_bit_cast(f16x8, t);
}
// relu + pack 16 f32 accum regs -> 8 u32 (f16x2); C reg 2i,2i+1 -> p[i]
__device__ __forceinline__ void packrelu(const f32x16& c, unsigned* p) {
    #pragma unroll
    for (int i = 0; i < 8; ++i)
        p[i] = pkru(c[2 * i], c[2 * i + 1]);
}
__device__ __forceinline__ float tanh_fast(float v) {
    v = fminf(fmaxf(v, -10.f), 10.f);
    float e = __expf(2.f * v);
    return __fdividef(e - 1.f, e + 1.f);
}

// ---------------------------------------------------------------------------
// Prep kernel: build permuted f16 A-fragments in d_ws. (same as R6)
// Frag map:
//   0,1     : gate L1 tiles (G1 + gb1 in phi_x bias slot)
//   2..5    : gate L2 steps 0-3 (G2)
//   6,7     : refine L1 tiles (R1 + rb1 in psi bias slot)
//   8..11   : refine L2 steps 0-3 (R2)
//   12+6e+0 : expert e W1 (phi_x + b1 bias slot)
//   12+6e+1,2: expert e W2 steps 0,1 (phi_h)
//   12+6e+3 : expert e b2 bias frag (slot h=0,j=0)
//   12+6e+4,5: expert e W3 steps 0,1 (phi_h), rows m<2
// ---------------------------------------------------------------------------
__global__ void prep_kernel(const float* __restrict__ W1, const float* __restrict__ b1,
                            const float* __restrict__ W2, const float* __restrict__ b2,
                            const float* __restrict__ W3, const float* __restrict__ b3,
                            const float* __restrict__ G1, const float* __restrict__ gb1,
                            const float* __restrict__ G2, const float* __restrict__ gb2,
                            const float* __restrict__ R1, const float* __restrict__ rb1,
                            const float* __restrict__ R2, const float* __restrict__ rb2,
                            _Float16* __restrict__ ws)
{
    int gid = blockIdx.x * 256 + threadIdx.x;
    if (gid >= NFRAG * 64) return;
    int f = gid >> 6, lane = gid & 63;
    int m = lane & 31, h = lane >> 5;
    float v[8];
    #pragma unroll
    for (int j = 0; j < 8; ++j) v[j] = 0.f;

    if (f < 2) {                       // gate L1, phi_x, tile m-offset f*32
        int mo = f * 32 + m;
        for (int j = 0; j < 8; ++j) {
            if (h == 0)       v[j] = G1[j * 64 + mo];
            else if (j < 2)   v[j] = G1[(8 + j) * 64 + mo];
            else if (j == 2)  v[j] = gb1[mo];
        }
    } else if (f < 6) {                // gate L2 (K=64), step s
        int s = f - 2;
        for (int j = 0; j < 8; ++j) {
            int k = 32 * (s >> 1) + 16 * (s & 1) + (j & 3) + 8 * (j >> 2) + 4 * h;
            v[j] = (m < 8) ? G2[k * 8 + m] : 0.f;
        }
    } else if (f < 8) {                // refine L1, psi, tile m-offset (f-6)*32
        int mo = (f - 6) * 32 + m;
        for (int j = 0; j < 8; ++j) {
            if (h == 0)       v[j] = R1[j * 64 + mo];        // rows 0,1=fused; 2..7=x0..x5
            else if (j < 4)   v[j] = R1[(8 + j) * 64 + mo];  // rows 8..11 = x6..x9
            else if (j == 4)  v[j] = rb1[mo];
        }
    } else if (f < 12) {               // refine L2 (K=64), step s
        int s = f - 8;
        for (int j = 0; j < 8; ++j) {
            int k = 32 * (s >> 1) + 16 * (s & 1) + (j & 3) + 8 * (j >> 2) + 4 * h;
            v[j] = (m < 2) ? R2[k * 2 + m] : 0.f;
        }
    } else {                           // experts
        int e = (f - 12) / 6, t = (f - 12) % 6;
        if (t == 0) {                  // W1 phi_x + b1
            for (int j = 0; j < 8; ++j) {
                if (h == 0)       v[j] = W1[e * 320 + j * 32 + m];
                else if (j < 2)   v[j] = W1[e * 320 + (8 + j) * 32 + m];
                else if (j == 2)  v[j] = b1[e * 32 + m];
            }
        } else if (t == 1 || t == 2) { // W2 step s, phi_h
            int s = t - 1;
            for (int j = 0; j < 8; ++j) {
                int k = 16 * s + (j & 3) + 8 * (j >> 2) + 4 * h;
                v[j] = W2[e * 1024 + k * 32 + m];
            }
        } else if (t == 3) {           // b2 bias frag
            if (h == 0) v[0] = b2[e * 32 + m];
        } else {                       // W3 step s, phi_h
            int s = t - 4;
            for (int j = 0; j < 8; ++j) {
                int k = 16 * s + (j & 3) + 8 * (j >> 2) + 4 * h;
                v[j] = (m < 2) ? W3[e * 64 + k * 2 + m] : 0.f;
            }
        }
    }
    _Float16* dst = ws + (size_t)(f * 64 + lane) * 8;
    #pragma unroll
    for (int j = 0; j < 8; ++j) dst[j] = (_Float16)v[j];
}

// ---------------------------------------------------------------------------
// Main kernel: block = 512 threads = 8 waves, 64 samples/wave (2 tiles).
// ---------------------------------------------------------------------------
__global__ __launch_bounds__(512, 1) void brain_mfma(
    const float* __restrict__ x,
    const u32x4v* __restrict__ wsf,
    const float* __restrict__ b3, const float* __restrict__ gb2,
    const float* __restrict__ rb2,
    float* __restrict__ out)
{
    __shared__ u32x4v smem[FRAG_U4];
    const int tid = threadIdx.x;
    for (int i = tid; i < FRAG_U4; i += 512) smem[i] = wsf[i];
    __syncthreads();

    const int lane = tid & 63;
    const int wv   = tid >> 6;
    const int n    = lane & 31;
    const int h    = lane >> 5;
    const size_t sA = (size_t)blockIdx.x * 512 + wv * 64 + n;   // tile A
    const size_t sB = sA + 32;                                   // tile B

    const unsigned ONEZERO = 0x00003C00u;  // f16 {1.0, 0.0}

    // ---- per-tile x load + fragment build ----
    const float2* xpA = (const float2*)(x + sA * 10);
    const float2* xpB = (const float2*)(x + sB * 10);
    float2 A0 = xpA[h ? 3 : 0], A1 = xpA[h ? 4 : 1], A2 = xpA[h ? 4 : 2], A3 = xpA[3];
    float2 B0 = xpB[h ? 3 : 0], B1 = xpB[h ? 4 : 1], B2 = xpB[h ? 4 : 2], B3 = xpB[3];

    unsigned pkAa = pkrtz_u(A0.x, A0.y), pkAb = pkrtz_u(A1.x, A1.y);
    unsigned pkAc = pkrtz_u(A2.x, A2.y), pkAd = pkrtz_u(A3.x, A3.y);
    unsigned pkBa = pkrtz_u(B0.x, B0.y), pkBb = pkrtz_u(B1.x, B1.y);
    unsigned pkBc = pkrtz_u(B2.x, B2.y), pkBd = pkrtz_u(B3.x, B3.y);

    // layer-1 x fragment (phi_x): lo {x0..x7}, hi {x8,x9,1,0,...}
    f16x8 xfA = h ? mk4(pkAb, ONEZERO, 0u, 0u) : mk4(pkAa, pkAb, pkAc, pkAd);
    f16x8 xfB = h ? mk4(pkBb, ONEZERO, 0u, 0u) : mk4(pkBa, pkBb, pkBc, pkBd);

    const f16x8 ONES = mk4(0x3C003C00u, 0x3C003C00u, 0x3C003C00u, 0x3C003C00u);
    f32x16 Z;
    #pragma unroll
    for (int i = 0; i < 16; ++i) Z[i] = 0.f;

    #define FRAG(F) __builtin_bit_cast(f16x8, smem[(F) * 64 + lane])

    // ---------------- gate (both tiles) ----------------
    float wA[8], wB[8];
    {
        f16x8 g0 = FRAG(0), g1 = FRAG(1);
        f32x16 cg0A = MFMA(g0, xfA, Z), cg1A = MFMA(g1, xfA, Z);
        f32x16 cg0B = MFMA(g0, xfB, Z), cg1B = MFMA(g1, xfB, Z);
        unsigned p0A[8], p1A[8], p0B[8], p1B[8];
        packrelu(cg0A, p0A); packrelu(cg1A, p1A);
        packrelu(cg0B, p0B); packrelu(cg1B, p1B);
        f16x8 l0 = FRAG(2), l1 = FRAG(3), l2 = FRAG(4), l3 = FRAG(5);
        f32x16 clA = MFMA(l0, mk4(p0A[0], p0A[1], p0A[2], p0A[3]), Z);
        clA = MFMA(l1, mk4(p0A[4], p0A[5], p0A[6], p0A[7]), clA);
        clA = MFMA(l2, mk4(p1A[0], p1A[1], p1A[2], p1A[3]), clA);
        clA = MFMA(l3, mk4(p1A[4], p1A[5], p1A[6], p1A[7]), clA);
        f32x16 clB = MFMA(l0, mk4(p0B[0], p0B[1], p0B[2], p0B[3]), Z);
        clB = MFMA(l1, mk4(p0B[4], p0B[5], p0B[6], p0B[7]), clB);
        clB = MFMA(l2, mk4(p1B[0], p1B[1], p1B[2], p1B[3]), clB);
        clB = MFMA(l3, mk4(p1B[4], p1B[5], p1B[6], p1B[7]), clB);

        // logits: low lanes regs0-3 = experts0-3; high lanes = experts4-7
        float lA[8], lB[8];
        #pragma unroll
        for (int j = 0; j < 4; ++j) {
            lA[j]     = clA[j] + gb2[j];
            lA[4 + j] = __shfl_xor(clA[j], 32) + gb2[4 + j];
            lB[j]     = clB[j] + gb2[j];
            lB[4 + j] = __shfl_xor(clB[j], 32) + gb2[4 + j];
        }
        float mxA = lA[0], mxB = lB[0];
        #pragma unroll
        for (int j = 1; j < 8; ++j) { mxA = fmaxf(mxA, lA[j]); mxB = fmaxf(mxB, lB[j]); }
        float sA_ = 0.f, sB_ = 0.f;
        #pragma unroll
        for (int j = 0; j < 8; ++j) {
            wA[j] = __expf(lA[j] - mxA); sA_ += wA[j];
            wB[j] = __expf(lB[j] - mxB); sB_ += wB[j];
        }
        float invA = __fdividef(1.f, sA_), invB = __fdividef(1.f, sB_);
        #pragma unroll
        for (int j = 0; j < 8; ++j) { wA[j] *= invA; wB[j] *= invB; }
    }

    // ---------------- experts (both tiles share frag reads) ----------------
    float fA0 = 0.f, fA1 = 0.f, fB0 = 0.f, fB1 = 0.f;
    #pragma unroll 1
    for (int e = 0; e < 8; ++e) {
        const int fb = 12 + e * 6;
        f16x8 a0 = FRAG(fb);
        f32x16 c1A = MFMA(a0, xfA, Z);
        f32x16 c1B = MFMA(a0, xfB, Z);
        unsigned qA[8], qB[8];
        packrelu(c1A, qA); packrelu(c1B, qB);

        f16x8 a1 = FRAG(fb + 1), a2 = FRAG(fb + 2), a3 = FRAG(fb + 3);
        f32x16 c2A = MFMA(a1, mk4(qA[0], qA[1], qA[2], qA[3]), Z);
        c2A = MFMA(a2, mk4(qA[4], qA[5], qA[6], qA[7]), c2A);
        c2A = MFMA(a3, ONES, c2A);                              // + b2
        f32x16 c2B = MFMA(a1, mk4(qB[0], qB[1], qB[2], qB[3]), Z);
        c2B = MFMA(a2, mk4(qB[4], qB[5], qB[6], qB[7]), c2B);
        c2B = MFMA(a3, ONES, c2B);
        packrelu(c2A, qA); packrelu(c2B, qB);

        f16x8 a4 = FRAG(fb + 4), a5 = FRAG(fb + 5);
        f32x16 c3A = MFMA(a4, mk4(qA[0], qA[1], qA[2], qA[3]), Z);
        c3A = MFMA(a5, mk4(qA[4], qA[5], qA[6], qA[7]), c3A);
        f32x16 c3B = MFMA(a4, mk4(qB[0], qB[1], qB[2], qB[3]), Z);
        c3B = MFMA(a5, mk4(qB[4], qB[5], qB[6], qB[7]), c3B);

        float b30 = b3[2 * e], b31 = b3[2 * e + 1];
        fA0 = fmaf(wA[e], tanh_fast(c3A[0] + b30), fA0);
        fA1 = fmaf(wA[e], tanh_fast(c3A[1] + b31), fA1);
        fB0 = fmaf(wB[e], tanh_fast(c3B[0] + b30), fB0);
        fB1 = fmaf(wB[e], tanh_fast(c3B[1] + b31), fB1);
    }

    // ---------------- refine (both tiles) ----------------
    // psi layout: lo {FUSED, x0x1, x2x3, x4x5}, hi {x6x7, x8x9, {1,0}, 0}
    unsigned rxA0 = h ? pkAa : pkrtz_u(fA0, fA1);
    unsigned rxB0 = h ? pkBa : pkrtz_u(fB0, fB1);
    unsigned rxA1 = h ? pkAb : pkAa, rxA2 = h ? ONEZERO : pkAb, rxA3 = h ? 0u : pkAc;
    unsigned rxB1 = h ? pkBb : pkBa, rxB2 = h ? ONEZERO : pkBb, rxB3 = h ? 0u : pkBc;
    f16x8 rfA = mk4(rxA0, rxA1, rxA2, rxA3);
    f16x8 rfB = mk4(rxB0, rxB1, rxB2, rxB3);

    f16x8 r0 = FRAG(6), r1 = FRAG(7);
    f32x16 cr0A = MFMA(r0, rfA, Z), cr1A = MFMA(r1, rfA, Z);
    f32x16 cr0B = MFMA(r0, rfB, Z), cr1B = MFMA(r1, rfB, Z);
    unsigned p0A[8], p1A[8], p0B[8], p1B[8];
    packrelu(cr0A, p0A); packrelu(cr1A, p1A);
    packrelu(cr0B, p0B); packrelu(cr1B, p1B);

    f16x8 d0 = FRAG(8), d1 = FRAG(9), d2 = FRAG(10), d3 = FRAG(11);
    f32x16 cdA = MFMA(d0, mk4(p0A[0], p0A[1], p0A[2], p0A[3]), Z);
    cdA = MFMA(d1, mk4(p0A[4], p0A[5], p0A[6], p0A[7]), cdA);
    cdA = MFMA(d2, mk4(p1A[0], p1A[1], p1A[2], p1A[3]), cdA);
    cdA = MFMA(d3, mk4(p1A[4], p1A[5], p1A[6], p1A[7]), cdA);
    f32x16 cdB = MFMA(d0, mk4(p0B[0], p0B[1], p0B[2], p0B[3]), Z);
    cdB = MFMA(d1, mk4(p0B[4], p0B[5], p0B[6], p0B[7]), cdB);
    cdB = MFMA(d2, mk4(p1B[0], p1B[1], p1B[2], p1B[3]), cdB);
    cdB = MFMA(d3, mk4(p1B[4], p1B[5], p1B[6], p1B[7]), cdB);

    if (h == 0) {
        float2 oA, oB;
        oA.x = tanh_fast(cdA[0] + rb2[0]);
        oA.y = tanh_fast(cdA[1] + rb2[1]);
        oB.x = tanh_fast(cdB[0] + rb2[0]);
        oB.y = tanh_fast(cdB[1] + rb2[1]);
        ((float2*)out)[sA] = oA;
        ((float2*)out)[sB] = oB;
    }
}

extern "C" void kernel_launch(void* const* d_in, const int* in_sizes, int n_in,
                              void* d_out, int out_size, void* d_ws, size_t ws_size,
                              hipStream_t stream) {
    const float* x   = (const float*)d_in[0];
    const float* W1  = (const float*)d_in[1];
    const float* b1  = (const float*)d_in[2];
    const float* W2  = (const float*)d_in[3];
    const float* b2  = (const float*)d_in[4];
    const float* W3  = (const float*)d_in[5];
    const float* b3  = (const float*)d_in[6];
    const float* G1  = (const float*)d_in[7];
    const float* gb1 = (const float*)d_in[8];
    const float* G2  = (const float*)d_in[9];
    const float* gb2 = (const float*)d_in[10];
    const float* R1  = (const float*)d_in[11];
    const float* rb1 = (const float*)d_in[12];
    const float* R2  = (const float*)d_in[13];
    const float* rb2 = (const float*)d_in[14];
    float* out = (float*)d_out;
    _Float16* ws = (_Float16*)d_ws;

    hipLaunchKernelGGL(prep_kernel, dim3(15), dim3(256), 0, stream,
                       W1, b1, W2, b2, W3, b3, G1, gb1, G2, gb2, R1, rb1, R2, rb2, ws);
    hipLaunchKernelGGL(brain_mfma, dim3(B_TOTAL / 512), dim3(512), 0, stream,
                       x, (const u32x4v*)ws, b3, gb2, rb2, out);
}